// Round 1
// baseline (433.515 us; speedup 1.0000x reference)
//
#include <hip/hip_runtime.h>

#define WAVES_PER_BLOCK 4
#define N_CH 128

__global__ __launch_bounds__(256) void roller_pool_kernel(
    const float* __restrict__ hidden,
    const int* __restrict__ target_size,
    float* __restrict__ out,
    int n_edges)
{
    // per-wave exclusive-csum strip: indices 0..128 used, pad to 132 to keep
    // strips from sharing a bank pattern
    __shared__ float cs[WAVES_PER_BLOCK][132];

    const int lane = threadIdx.x & 63;
    const int wave = threadIdx.x >> 6;
    const int wave_global = blockIdx.x * WAVES_PER_BLOCK + wave;
    const int wave_stride = gridDim.x * WAVES_PER_BLOCK;
    float* mycs = cs[wave];

    for (int e = wave_global; e < n_edges; e += wave_stride) {
        const size_t row = (size_t)e * N_CH;
        const float2 v = *reinterpret_cast<const float2*>(hidden + row + lane * 2);
        const float a = v.x;
        const float b = v.y;

        // inclusive scan of per-lane pair-sum across the 64-lane wave
        float s = a + b;
        #pragma unroll
        for (int off = 1; off < 64; off <<= 1) {
            float t = __shfl_up(s, off, 64);
            if (lane >= off) s += t;
        }
        // s = sum(hidden[0 .. 2*lane+1])  (inclusive through this lane's pair)

        // exclusive csum: cs[k] = sum(hidden[0..k-1]), k = 0..128
        mycs[2 * lane + 1] = s - b;   // prefix through element 2*lane
        mycs[2 * lane + 2] = s;       // prefix through element 2*lane+1
        if (lane == 0) mycs[0] = 0.0f;
        __threadfence_block();        // order LDS write -> read (wave-local, no barrier)

        const int w = N_CH - (target_size[e] - 1);   // window size, 1..128
        const float inv_w = 1.0f / (float)w;

        const int j0 = 2 * lane;
        const int j1 = j0 + 1;
        const int e0 = min(j0 + w, N_CH);
        const int e1 = min(j1 + w, N_CH);

        float2 o;
        o.x = (mycs[e0] - mycs[j0]) * inv_w;
        o.y = (mycs[e1] - mycs[j1]) * inv_w;
        *reinterpret_cast<float2*>(out + row + lane * 2) = o;
    }
}

extern "C" void kernel_launch(void* const* d_in, const int* in_sizes, int n_in,
                              void* d_out, int out_size, void* d_ws, size_t ws_size,
                              hipStream_t stream) {
    const float* hidden = (const float*)d_in[0];
    const int* target_size = (const int*)d_in[1];
    float* out = (float*)d_out;

    const int n_edges = in_sizes[1];          // target_size has one entry per edge
    const int waves_needed = (n_edges + WAVES_PER_BLOCK - 1) / WAVES_PER_BLOCK;
    int blocks = waves_needed < 2048 ? waves_needed : 2048;

    roller_pool_kernel<<<blocks, WAVES_PER_BLOCK * 64, 0, stream>>>(
        hidden, target_size, out, n_edges);
}